// Round 4
// baseline (112.325 us; speedup 1.0000x reference)
//
#include <hip/hip_runtime.h>
#include <hip/hip_bf16.h>

#define BB 4
#define QQ 512
#define MM 8192
#define DD 8
#define EE 512
#define SS 256

using f32x4  = __attribute__((ext_vector_type(4))) float;
using bf16x8 = __attribute__((ext_vector_type(8))) short;

static __device__ __forceinline__ unsigned short f2bf(float f) {
  union { __hip_bfloat16 h; unsigned short u; } v;
  v.h = __float2bfloat16(f);
  return v.u;
}

// ---------------------------------------------------------------------------
// K1: log-affinity (log2 domain) + row max + unnormalized exp2 -> bf16 wts,
//     plus per-row 1/sum -> inv[]  (normalization folded into K4 epilogue).
// ---------------------------------------------------------------------------
#define QT 2
#define K1_T 512
#define K1_I (MM / K1_T)   // 16

__global__ __launch_bounds__(512) void k_aff(
    const float* __restrict__ loc, const float* __restrict__ locsd,
    const float* __restrict__ mloc, const float* __restrict__ msd,
    unsigned short* __restrict__ wts, float* __restrict__ inv)
{
  __shared__ float la_s[QT * K1_I * K1_T];   // 64 KB
  __shared__ float red[QT][8];

  const int blk = blockIdx.x;
  const int b   = blk / (QQ / QT);
  const int q0  = (blk % (QQ / QT)) * QT;
  const int t   = threadIdx.x;
  const int lane = t & 63;
  const int wv   = t >> 6;

  float lx[QT][DD], ls2[QT][DD];
#pragma unroll
  for (int qi = 0; qi < QT; ++qi)
#pragma unroll
    for (int d = 0; d < DD; ++d) {
      const int base = ((b * QQ) + q0 + qi) * DD + d;
      lx[qi][d] = loc[base];
      float s = locsd[base];
      ls2[qi][d] = __builtin_fmaf(s, s, 1e-8f);   // fold eps here (exact)
    }

  const float4* ml4 = reinterpret_cast<const float4*>(mloc + (size_t)b * MM * DD);
  const float4* ms4 = reinterpret_cast<const float4*>(msd  + (size_t)b * MM * DD);

  // lavp = 0.5*log2e*ssum + log2(prod v);  log_aff/ln2 = -lavp + const
  float mn[QT] = {3.4e38f, 3.4e38f};           // track min(lavp) == -max(la2)

#pragma unroll
  for (int i = 0; i < K1_I; ++i) {
    const int m = i * K1_T + t;
    float4 a0 = ml4[2 * m], a1 = ml4[2 * m + 1];
    float4 s0 = ms4[2 * m], s1 = ms4[2 * m + 1];
    float mlv[DD] = {a0.x, a0.y, a0.z, a0.w, a1.x, a1.y, a1.z, a1.w};
    float msv[DD] = {s0.x, s0.y, s0.z, s0.w, s1.x, s1.y, s1.z, s1.w};
    float ms2[DD];
#pragma unroll
    for (int d = 0; d < DD; ++d) ms2[d] = msv[d] * msv[d];
#pragma unroll
    for (int qi = 0; qi < QT; ++qi) {
      float ssum = 0.f, p = 1.f;
#pragma unroll
      for (int d = 0; d < DD; ++d) {
        float v  = ls2[qi][d] + ms2[d];
        float r  = __builtin_amdgcn_rcpf(v);
        float dl = lx[qi][d] - mlv[d];
        float d2 = dl * dl;
        float tt = d2 * r;
        ssum = __builtin_fmaf(tt, tt, ssum);
        p *= v;
      }
      float lavp = __builtin_fmaf(ssum, 0.72134752f, __builtin_amdgcn_logf(p));
      mn[qi] = fminf(mn[qi], lavp);
      la_s[(qi * K1_I + i) * K1_T + t] = lavp;
    }
  }

  // block-wide min(lavp)
#pragma unroll
  for (int qi = 0; qi < QT; ++qi)
#pragma unroll
    for (int off = 32; off; off >>= 1)
      mn[qi] = fminf(mn[qi], __shfl_xor(mn[qi], off, 64));
  if (lane == 0) { red[0][wv] = mn[0]; red[1][wv] = mn[1]; }
  __syncthreads();
  float mnb[QT];
#pragma unroll
  for (int qi = 0; qi < QT; ++qi) {
    float m2 = red[qi][0];
#pragma unroll
    for (int w = 1; w < 8; ++w) m2 = fminf(m2, red[qi][w]);
    mnb[qi] = m2;
  }
  __syncthreads();   // red about to be reused

  float sm[QT] = {0.f, 0.f};
#pragma unroll
  for (int i = 0; i < K1_I; ++i) {
    const int m = i * K1_T + t;
#pragma unroll
    for (int qi = 0; qi < QT; ++qi) {
      float lv = la_s[(qi * K1_I + i) * K1_T + t];
      float e  = __builtin_amdgcn_exp2f(mnb[qi] - lv);   // la2 - max2
      sm[qi] += e;
      wts[((size_t)(b * QQ + q0 + qi)) * MM + m] = f2bf(e);
    }
  }
#pragma unroll
  for (int qi = 0; qi < QT; ++qi)
#pragma unroll
    for (int off = 32; off; off >>= 1)
      sm[qi] += __shfl_xor(sm[qi], off, 64);
  if (lane == 0) { red[0][wv] = sm[0]; red[1][wv] = sm[1]; }
  __syncthreads();
  if (t == 0) {
#pragma unroll
    for (int qi = 0; qi < QT; ++qi) {
      float s = 0.f;
#pragma unroll
      for (int w = 0; w < 8; ++w) s += red[qi][w];
      inv[b * QQ + q0 + qi] = 1.0f / s;
    }
  }
}

// ---------------------------------------------------------------------------
// K2: projT[b][s][m] = sum_e W[s][e] * V[b][m][e]; f32 in, bf16 out.
// 128x128 tile, BK=64, 256 thr (4 waves 2x2), 2-phase reg-staged pipeline.
// ---------------------------------------------------------------------------
__global__ __launch_bounds__(256) void k_proj(
    const float* __restrict__ V, const float* __restrict__ W,
    unsigned short* __restrict__ projT)
{
  const int m0 = blockIdx.x * 128;
  const int s0 = blockIdx.y * 128;
  const int b  = blockIdx.z;
  const int t = threadIdx.x, lane = t & 63, wv = t >> 6;
  const int wr = wv >> 1, wc = wv & 1;

  __shared__ short lA[128 * 64];
  __shared__ short lB[128 * 64];

  f32x4 acc[4][4] = {};

  const float* Wp = W + (size_t)s0 * EE;
  const float* Vp = V + (size_t)b * MM * EE + (size_t)m0 * EE;

  const int r0 = t >> 4;          // 0..15
  const int c0 = (t & 15) * 4;    // float col
  const int swz = (r0 & 7) << 3;

  float4 ra[8], rb[8];

#define P_LOADS(K0)                                                        \
  _Pragma("unroll")                                                        \
  for (int j = 0; j < 8; ++j) {                                            \
    const int row = j * 16 + r0;                                           \
    ra[j] = *reinterpret_cast<const float4*>(&Wp[(size_t)row * EE + (K0) + c0]); \
    rb[j] = *reinterpret_cast<const float4*>(&Vp[(size_t)row * EE + (K0) + c0]); \
  }

  P_LOADS(0)

  for (int ki = 0; ki < 8; ++ki) {
    __syncthreads();
#pragma unroll
    for (int j = 0; j < 8; ++j) {
      const int row = j * 16 + r0;
      const int idx = (row * 64 + c0) ^ swz;
      ushort4 da, db;
      da.x = f2bf(ra[j].x); da.y = f2bf(ra[j].y); da.z = f2bf(ra[j].z); da.w = f2bf(ra[j].w);
      db.x = f2bf(rb[j].x); db.y = f2bf(rb[j].y); db.z = f2bf(rb[j].z); db.w = f2bf(rb[j].w);
      *reinterpret_cast<ushort4*>(&lA[idx]) = da;
      *reinterpret_cast<ushort4*>(&lB[idx]) = db;
    }
    if (ki < 7) { P_LOADS((ki + 1) * 64) }   // in flight under MFMA phase
    __syncthreads();

#pragma unroll
    for (int kk = 0; kk < 2; ++kk) {
      const int kofs = kk * 32 + (lane >> 4) * 8;
      const int r15 = lane & 15;
      bf16x8 af[4], bfv[4];
#pragma unroll
      for (int mi = 0; mi < 4; ++mi) {
        int row = wr * 64 + mi * 16 + r15;
        af[mi] = *reinterpret_cast<const bf16x8*>(&lA[(row * 64 + kofs) ^ ((row & 7) << 3)]);
      }
#pragma unroll
      for (int ni = 0; ni < 4; ++ni) {
        int row = wc * 64 + ni * 16 + r15;
        bfv[ni] = *reinterpret_cast<const bf16x8*>(&lB[(row * 64 + kofs) ^ ((row & 7) << 3)]);
      }
#pragma unroll
      for (int mi = 0; mi < 4; ++mi)
#pragma unroll
        for (int ni = 0; ni < 4; ++ni)
          acc[mi][ni] = __builtin_amdgcn_mfma_f32_16x16x32_bf16(af[mi], bfv[ni], acc[mi][ni], 0, 0, 0);
    }
  }
#undef P_LOADS

  unsigned short* outp = projT + (size_t)b * SS * MM;
  const int fr = (lane >> 4) * 4;
  const int fc = lane & 15;
#pragma unroll
  for (int mi = 0; mi < 4; ++mi)
#pragma unroll
    for (int ni = 0; ni < 4; ++ni)
#pragma unroll
      for (int r = 0; r < 4; ++r) {
        int s = s0 + wr * 64 + mi * 16 + fr + r;
        int m = m0 + wc * 64 + ni * 16 + fc;
        outp[(size_t)s * MM + m] = f2bf(acc[mi][ni][r]);
      }
}

// ---------------------------------------------------------------------------
// K3: part[ks][bu][t][c] = fragment-layout f32 partials of
//     sum_{m in slice ks} wts[b][q][m] * projT[b][s][m]
// 128x128 tile, BK=64, runtime K-split, XCD-chunked ks-major block swizzle.
// part chunk: slice ks (PSLICE f32) -> block-unit bu=tile*4+b (16384 f32)
//   -> chunk c=mi*4+ni (1024 f32) -> thread t (4 f32 = acc[mi][ni] f32x4).
// ---------------------------------------------------------------------------
#define PSLICE ((size_t)BB * QQ * SS)   // f32 elements per ks slice (524288)

__global__ __launch_bounds__(256) void k_wgemm(
    const unsigned short* __restrict__ wts,
    const unsigned short* __restrict__ projT,
    float* __restrict__ part, int ksn, int mslice)
{
  // XCD-chunked swizzle: hw blocks with same (hw&7) share an XCD (round-robin);
  // give each XCD a contiguous ks-major virtual range -> per-XCD working set
  // = 2 ks slices (~6 MB) -> wts/projT fetched ~once.
  const int nblk8 = ksn * 4;                 // (32*ksn)/8
  const int hw   = blockIdx.x;
  const int virt = (hw & 7) * nblk8 + (hw >> 3);
  const int ks   = virt >> 5;
  const int tile = virt & 7;                 // 0..7 : 4 q-tiles x 2 s-tiles
  const int b    = (virt >> 3) & 3;

  const int q0 = (tile >> 1) * 128;
  const int s0 = (tile & 1) * 128;
  const int kbeg  = ks * mslice;
  const int niter = mslice >> 6;
  const int t = threadIdx.x, lane = t & 63, wv = t >> 6;
  const int wr = wv >> 1, wc = wv & 1;

  __shared__ short lA[128 * 64];
  __shared__ short lB[128 * 64];

  f32x4 acc[4][4] = {};
  const unsigned short* A  = wts   + (size_t)b * QQ * MM + (size_t)q0 * MM;
  const unsigned short* Bp = projT + (size_t)b * SS * MM + (size_t)s0 * MM;

  const int r0 = t >> 3;        // 0..31
  const int c0 = (t & 7) * 8;   // short col
  const int swz = (r0 & 7) << 3;

  uint4 ua[4], ub[4];

#define G_LOADS(K0)                                                         \
  _Pragma("unroll")                                                         \
  for (int j = 0; j < 4; ++j) {                                             \
    const int row = j * 32 + r0;                                            \
    ua[j] = *reinterpret_cast<const uint4*>(&A[(size_t)row * MM + (K0) + c0]);  \
    ub[j] = *reinterpret_cast<const uint4*>(&Bp[(size_t)row * MM + (K0) + c0]); \
  }

  G_LOADS(kbeg)

  for (int ki = 0; ki < niter; ++ki) {
    __syncthreads();
#pragma unroll
    for (int j = 0; j < 4; ++j) {
      const int row = j * 32 + r0;
      const int idx = (row * 64 + c0) ^ swz;
      *reinterpret_cast<uint4*>(&lA[idx]) = ua[j];
      *reinterpret_cast<uint4*>(&lB[idx]) = ub[j];
    }
    if (ki + 1 < niter) { G_LOADS(kbeg + (ki + 1) * 64) }
    __syncthreads();

#pragma unroll
    for (int kk = 0; kk < 2; ++kk) {
      const int kofs = kk * 32 + (lane >> 4) * 8;
      const int r15 = lane & 15;
      bf16x8 af[4], bfv[4];
#pragma unroll
      for (int mi = 0; mi < 4; ++mi) {
        int row = wr * 64 + mi * 16 + r15;
        af[mi] = *reinterpret_cast<const bf16x8*>(&lA[(row * 64 + kofs) ^ ((row & 7) << 3)]);
      }
#pragma unroll
      for (int ni = 0; ni < 4; ++ni) {
        int row = wc * 64 + ni * 16 + r15;
        bfv[ni] = *reinterpret_cast<const bf16x8*>(&lB[(row * 64 + kofs) ^ ((row & 7) << 3)]);
      }
#pragma unroll
      for (int mi = 0; mi < 4; ++mi)
#pragma unroll
        for (int ni = 0; ni < 4; ++ni)
          acc[mi][ni] = __builtin_amdgcn_mfma_f32_16x16x32_bf16(af[mi], bfv[ni], acc[mi][ni], 0, 0, 0);
    }
  }
#undef G_LOADS

  // fragment-native coalesced epilogue: 16 x (16B lane-contiguous) stores
  float* pp = part + (size_t)ks * PSLICE + (size_t)(tile * 4 + b) * 16384 + (size_t)t * 4;
#pragma unroll
  for (int mi = 0; mi < 4; ++mi)
#pragma unroll
    for (int ni = 0; ni < 4; ++ni)
      *reinterpret_cast<float4*>(pp + (size_t)(mi * 4 + ni) * 1024) =
          *reinterpret_cast<float4*>(&acc[mi][ni]);
}

// ---------------------------------------------------------------------------
// K4: out[b][q][s] = inv[b][q] * sum_ks part[ks][bu][t][c]
// grid (32, 8): bu = tile*4+b, y = chunk pair. Reads fully linear.
// ---------------------------------------------------------------------------
__global__ __launch_bounds__(256) void k_reduce(
    const float4* __restrict__ part4,
    const float* __restrict__ inv,
    float* __restrict__ out, int ksn)
{
  const int bu = blockIdx.x;            // tile*4 + b
  const int tile = bu >> 2, b = bu & 3;
  const int q0 = (tile >> 1) * 128, s0 = (tile & 1) * 128;
  const int t = threadIdx.x, lane = t & 63, wv = t >> 6;
  const int wr = wv >> 1, wc = wv & 1;
  const size_t base4 = (size_t)bu * 4096 + t;   // float4 units

#pragma unroll
  for (int ci = 0; ci < 2; ++ci) {
    const int c = blockIdx.y * 2 + ci;
    const int mi = c >> 2, ni = c & 3;
    float4 a = {0.f, 0.f, 0.f, 0.f};
#pragma unroll 4
    for (int ks = 0; ks < ksn; ++ks) {
      float4 v = part4[(size_t)ks * (PSLICE / 4) + base4 + (size_t)c * 256];
      a.x += v.x; a.y += v.y; a.z += v.z; a.w += v.w;
    }
    const int qb = q0 + wr * 64 + mi * 16 + (lane >> 4) * 4;
    const int s  = s0 + wc * 64 + ni * 16 + (lane & 15);
    float* op = out + (size_t)(b * QQ + qb) * SS + s;
    const float* ivp = inv + b * QQ + qb;
    op[0 * SS] = a.x * ivp[0];
    op[1 * SS] = a.y * ivp[1];
    op[2 * SS] = a.z * ivp[2];
    op[3 * SS] = a.w * ivp[3];
  }
}

// ---------------------------------------------------------------------------

extern "C" void kernel_launch(void* const* d_in, const int* in_sizes, int n_in,
                              void* d_out, int out_size, void* d_ws, size_t ws_size,
                              hipStream_t stream) {
  const float* loc    = (const float*)d_in[0];
  const float* locsd  = (const float*)d_in[1];
  const float* mloc   = (const float*)d_in[2];
  const float* msd    = (const float*)d_in[3];
  const float* msense = (const float*)d_in[4];
  const float* wread  = (const float*)d_in[5];
  float* out = (float*)d_out;

  const size_t wts_bytes  = (size_t)BB * QQ * MM * 2;   // 33.5 MB
  const size_t proj_bytes = (size_t)BB * SS * MM * 2;   // 16.8 MB
  const size_t inv_bytes  = (size_t)BB * QQ * 4;        // 8 KB
  const size_t slice_bytes = PSLICE * 4;                // 2.1 MB per ks slice

  const size_t fixed = wts_bytes + proj_bytes + inv_bytes;
  if (ws_size < fixed + 4 * slice_bytes) return;        // need at least KSPLIT=4
  int ksn = 4;
  if (ws_size >= fixed + 16 * slice_bytes) ksn = 16;
  else if (ws_size >= fixed + 8 * slice_bytes) ksn = 8;

  unsigned short* wts   = (unsigned short*)d_ws;
  unsigned short* projT = (unsigned short*)((char*)d_ws + wts_bytes);
  float*          inv   = (float*)((char*)d_ws + wts_bytes + proj_bytes);
  float*          part  = (float*)((char*)d_ws + fixed);

  hipLaunchKernelGGL(k_aff, dim3(BB * QQ / QT), dim3(K1_T), 0, stream,
                     loc, locsd, mloc, msd, wts, inv);
  hipLaunchKernelGGL(k_proj, dim3(MM / 128, SS / 128, BB), dim3(256), 0, stream,
                     msense, wread, projT);
  hipLaunchKernelGGL(k_wgemm, dim3(32 * ksn), dim3(256), 0, stream,
                     wts, projT, part, ksn, MM / ksn);
  hipLaunchKernelGGL(k_reduce, dim3(32, 8), dim3(256), 0, stream,
                     (const float4*)part, inv, out, ksn);
}